// Round 1
// baseline (187.096 us; speedup 1.0000x reference)
//
#include <hip/hip_runtime.h>

#define THREADS 256
#define WAVES_PER_BLOCK 4
#define ROW_LEN 512

__device__ __forceinline__ float wave_reduce_max(float v) {
#pragma unroll
    for (int o = 32; o > 0; o >>= 1) v = fmaxf(v, __shfl_xor(v, o));
    return v;
}
__device__ __forceinline__ float wave_reduce_sum(float v) {
#pragma unroll
    for (int o = 32; o > 0; o >>= 1) v += __shfl_xor(v, o);
    return v;
}

// PASS 0: compute global absmax of softmax_out via per-row reductions + one atomic per block.
// PASS 1: recompute softmax_out, apply per-tensor int8 fake-quant, write result.
template <int PASS>
__global__ __launch_bounds__(THREADS) void pla_softmax_kernel(
    const float* __restrict__ scores,
    const float* __restrict__ coeffs_m,
    const float* __restrict__ coeffs_c,
    const float* __restrict__ intervals,
    float* __restrict__ out,
    unsigned* __restrict__ absmax_bits,
    int nrows)
{
    __shared__ float2 s_mc[12];          // (m, c) per interval, gathered by runtime idx
    __shared__ float  s_blockmax[WAVES_PER_BLOCK];

    const int tid = threadIdx.x;
    if (tid < 12) s_mc[tid] = make_float2(coeffs_m[tid], coeffs_c[tid]);
    __syncthreads();

    const int wave = tid >> 6;
    const int lane = tid & 63;
    const int row  = blockIdx.x * WAVES_PER_BLOCK + wave;
    if (row >= nrows) return;

    // Interval lower edges 1..11 -> uniform address loads -> SGPRs (edge 0 = -10 is implied:
    // after the clip below, xc >= -10 always, matching searchsorted side='right' minus 1).
    float aedge[11];
#pragma unroll
    for (int i = 0; i < 11; ++i) aedge[i] = intervals[i + 1];

    // Coalesced row load: lane covers elems [4*lane, 4*lane+4) and [256+4*lane, ...).
    const float4* rp = reinterpret_cast<const float4*>(scores + (size_t)row * ROW_LEN);
    float4 v0 = rp[lane];
    float4 v1 = rp[lane + 64];
    float x[8] = {v0.x, v0.y, v0.z, v0.w, v1.x, v1.y, v1.z, v1.w};

    // Row max
    float mx = fmaxf(fmaxf(fmaxf(x[0], x[1]), fmaxf(x[2], x[3])),
                     fmaxf(fmaxf(x[4], x[5]), fmaxf(x[6], x[7])));
    mx = wave_reduce_max(mx);

    // PLA exp per element
    float e[8];
    float sum = 0.0f, ma = 0.0f;
#pragma unroll
    for (int j = 0; j < 8; ++j) {
        float sh = x[j] - mx;
        float t = rintf(sh * 67108864.0f);                 // Q32.26 snap, round-half-even
        t = fminf(fmaxf(t, -2147483648.0f), 2147483648.0f); // jnp clip bounds (2^31-1 rounds to 2^31 in f32)
        float fx = t * 1.4901161193847656e-8f;             // exact * 2^-26
        float xc = fminf(fmaxf(fx, -10.0f), 0.0f);
        int cnt = 0;
#pragma unroll
        for (int i = 0; i < 11; ++i) cnt += (xc >= aedge[i]) ? 1 : 0;
        int idx = min(cnt, 10);                            // reference clamps to len(intervals)-2
        float2 p = s_mc[idx];
        float ev = p.x * xc + p.y;
        e[j] = ev;
        sum += ev;
        ma = fmaxf(ma, fabsf(ev));
    }
    sum = wave_reduce_sum(sum);
    const float S = sum + 1e-9f;

    if (PASS == 0) {
        ma = wave_reduce_max(ma);
        if (lane == 0) s_blockmax[wave] = ma / S;          // per-row max |softmax_out|
        __syncthreads();
        if (tid == 0) {
            float bm = s_blockmax[0];
#pragma unroll
            for (int w = 1; w < WAVES_PER_BLOCK; ++w) bm = fmaxf(bm, s_blockmax[w]);
            // non-negative floats: uint bit-pattern ordering == float ordering
            atomicMax(absmax_bits, __float_as_uint(bm));
        }
    } else {
        const float inv = 1.0f / S;
        const float am = __uint_as_float(*absmax_bits);
        const float scale = fmaxf(am / 127.0f, 1e-8f);
        const float iscale = 1.0f / scale;
        float o[8];
#pragma unroll
        for (int j = 0; j < 8; ++j) {
            float sv = e[j] * inv;
            float q = fminf(fmaxf(rintf(sv * iscale), -127.0f), 127.0f) * scale;
            o[j] = q;                                      // STE forward value == q
        }
        float4* op = reinterpret_cast<float4*>(out + (size_t)row * ROW_LEN);
        op[lane]      = make_float4(o[0], o[1], o[2], o[3]);
        op[lane + 64] = make_float4(o[4], o[5], o[6], o[7]);
    }
}

extern "C" void kernel_launch(void* const* d_in, const int* in_sizes, int n_in,
                              void* d_out, int out_size, void* d_ws, size_t ws_size,
                              hipStream_t stream) {
    const float* scores    = (const float*)d_in[0];
    const float* coeffs_m  = (const float*)d_in[1];
    const float* coeffs_c  = (const float*)d_in[2];
    const float* intervals = (const float*)d_in[3];
    float* out = (float*)d_out;
    unsigned* absmax_bits = (unsigned*)d_ws;

    const int nrows  = in_sizes[0] / ROW_LEN;
    const int blocks = (nrows + WAVES_PER_BLOCK - 1) / WAVES_PER_BLOCK;

    // ws is poisoned (0xAA) once before timing and never re-poisoned; zero the
    // absmax slot every launch so atomicMax starts clean (deterministic).
    hipMemsetAsync(d_ws, 0, sizeof(unsigned), stream);

    pla_softmax_kernel<0><<<blocks, THREADS, 0, stream>>>(
        scores, coeffs_m, coeffs_c, intervals, out, absmax_bits, nrows);
    pla_softmax_kernel<1><<<blocks, THREADS, 0, stream>>>(
        scores, coeffs_m, coeffs_c, intervals, out, absmax_bits, nrows);
}

// Round 2
// 68.697 us; speedup vs baseline: 2.7235x; 2.7235x over previous
//
#include <hip/hip_runtime.h>

#define THREADS 256
#define WAVES_PER_BLOCK 4
#define ROW_LEN 512
#define NSLOTS 64
#define SLOT_STRIDE 32   // floats; 128 B between slots -> no same-line contention

__device__ __forceinline__ float wave_reduce_max(float v) {
#pragma unroll
    for (int o = 32; o > 0; o >>= 1) v = fmaxf(v, __shfl_xor(v, o));
    return v;
}
__device__ __forceinline__ float wave_reduce_sum(float v) {
#pragma unroll
    for (int o = 32; o > 0; o >>= 1) v += __shfl_xor(v, o);
    return v;
}

// PASS 0: per-row sum S; candidate global absmax = c10 / S (row max element snaps
//         to xc == 0 exactly, so max|e| per row == coeffs_c[10]); scatter via
//         64 spread atomicMax slots (no same-address serialization).
// PASS 1: recompute softmax_out, reduce the 64 slots -> scale, fake-quant, write.
template <int PASS>
__global__ __launch_bounds__(THREADS) void pla_softmax_kernel(
    const float* __restrict__ scores,
    const float* __restrict__ coeffs_m,
    const float* __restrict__ coeffs_c,
    const float* __restrict__ intervals,
    float* __restrict__ out,
    unsigned* __restrict__ slots,
    int nrows)
{
    __shared__ float2 s_mc[12];          // (m, c) per interval, gathered by runtime idx
    __shared__ float  s_blockmax[WAVES_PER_BLOCK];

    const int tid = threadIdx.x;
    if (tid < 12) s_mc[tid] = make_float2(coeffs_m[tid], coeffs_c[tid]);
    __syncthreads();

    const int wave = tid >> 6;
    const int lane = tid & 63;
    const int row  = blockIdx.x * WAVES_PER_BLOCK + wave;
    if (row >= nrows) return;

    // Interval lower edges 1..11 -> uniform loads -> SGPRs (edge 0 = -10 implied by clip).
    float aedge[11];
#pragma unroll
    for (int i = 0; i < 11; ++i) aedge[i] = intervals[i + 1];

    // Coalesced row load: lane covers elems [4*lane, 4*lane+4) and [256+4*lane, ...).
    const float4* rp = reinterpret_cast<const float4*>(scores + (size_t)row * ROW_LEN);
    float4 v0 = rp[lane];
    float4 v1 = rp[lane + 64];
    float x[8] = {v0.x, v0.y, v0.z, v0.w, v1.x, v1.y, v1.z, v1.w};

    // Row max
    float mx = fmaxf(fmaxf(fmaxf(x[0], x[1]), fmaxf(x[2], x[3])),
                     fmaxf(fmaxf(x[4], x[5]), fmaxf(x[6], x[7])));
    mx = wave_reduce_max(mx);

    // PLA exp per element
    float e[8];
    float sum = 0.0f;
#pragma unroll
    for (int j = 0; j < 8; ++j) {
        float sh = x[j] - mx;
        float t = rintf(sh * 67108864.0f);                  // Q32.26 snap, round-half-even
        t = fminf(fmaxf(t, -2147483648.0f), 2147483648.0f); // jnp clip bounds
        float fx = t * 1.4901161193847656e-8f;              // exact * 2^-26
        float xc = fminf(fmaxf(fx, -10.0f), 0.0f);
        int cnt = 0;
#pragma unroll
        for (int i = 0; i < 11; ++i) cnt += (xc >= aedge[i]) ? 1 : 0;
        int idx = min(cnt, 10);                             // reference clamps to len-2
        float2 p = s_mc[idx];
        float ev = p.x * xc + p.y;
        e[j] = ev;
        sum += ev;
    }
    sum = wave_reduce_sum(sum);
    const float S = sum + 1e-9f;

    if (PASS == 0) {
        // max|softmax_out| for this row == c10 / S  (see header comment)
        if (lane == 0) s_blockmax[wave] = coeffs_c[10] / S;
        __syncthreads();
        if (tid == 0) {
            float bm = s_blockmax[0];
#pragma unroll
            for (int w = 1; w < WAVES_PER_BLOCK; ++w) bm = fmaxf(bm, s_blockmax[w]);
            // non-negative floats: uint bit ordering == float ordering
            atomicMax(&slots[(blockIdx.x & (NSLOTS - 1)) * SLOT_STRIDE],
                      __float_as_uint(bm));
        }
    } else {
        // Reduce the 64 slots (each lane reads its own slot -> 6 shuffles)
        float am = __uint_as_float(slots[lane * SLOT_STRIDE]);
        am = wave_reduce_max(am);

        const float inv = 1.0f / S;
        const float scale = fmaxf(am / 127.0f, 1e-8f);
        const float iscale = 1.0f / scale;
        float o[8];
#pragma unroll
        for (int j = 0; j < 8; ++j) {
            float sv = e[j] * inv;
            float q = fminf(fmaxf(rintf(sv * iscale), -127.0f), 127.0f) * scale;
            o[j] = q;                                       // STE forward value == q
        }
        float4* op = reinterpret_cast<float4*>(out + (size_t)row * ROW_LEN);
        op[lane]      = make_float4(o[0], o[1], o[2], o[3]);
        op[lane + 64] = make_float4(o[4], o[5], o[6], o[7]);
    }
}

extern "C" void kernel_launch(void* const* d_in, const int* in_sizes, int n_in,
                              void* d_out, int out_size, void* d_ws, size_t ws_size,
                              hipStream_t stream) {
    const float* scores    = (const float*)d_in[0];
    const float* coeffs_m  = (const float*)d_in[1];
    const float* coeffs_c  = (const float*)d_in[2];
    const float* intervals = (const float*)d_in[3];
    float* out = (float*)d_out;
    unsigned* slots = (unsigned*)d_ws;

    const int nrows  = in_sizes[0] / ROW_LEN;
    const int blocks = (nrows + WAVES_PER_BLOCK - 1) / WAVES_PER_BLOCK;

    // Zero the atomic slots every launch (ws is poisoned once, never restored).
    hipMemsetAsync(d_ws, 0, NSLOTS * SLOT_STRIDE * sizeof(unsigned), stream);

    pla_softmax_kernel<0><<<blocks, THREADS, 0, stream>>>(
        scores, coeffs_m, coeffs_c, intervals, out, slots, nrows);
    pla_softmax_kernel<1><<<blocks, THREADS, 0, stream>>>(
        scores, coeffs_m, coeffs_c, intervals, out, slots, nrows);
}

// Round 3
// 68.641 us; speedup vs baseline: 2.7257x; 1.0008x over previous
//
#include <hip/hip_runtime.h>

#define THREADS 256
#define WAVES_PER_BLOCK 4
#define ROW_LEN 512

__device__ __forceinline__ float wave_reduce_max(float v) {
#pragma unroll
    for (int o = 32; o > 0; o >>= 1) v = fmaxf(v, __shfl_xor(v, o));
    return v;
}
__device__ __forceinline__ float wave_reduce_sum(float v) {
#pragma unroll
    for (int o = 32; o > 0; o >>= 1) v += __shfl_xor(v, o);
    return v;
}

// PASS 0: per-row sum S; per-block candidate absmax = max_w(c10 / S_w) stored
//         NON-atomically to slots[blockIdx.x] (fully overwritten every launch,
//         so no ws zeroing / no memset / no atomics needed).
// PASS 1: recompute softmax_out, read the pre-reduced global absmax scalar,
//         fake-quant, write.
template <int PASS>
__global__ __launch_bounds__(THREADS) void pla_softmax_kernel(
    const float* __restrict__ scores,
    const float* __restrict__ coeffs_m,
    const float* __restrict__ coeffs_c,
    const float* __restrict__ intervals,
    float* __restrict__ out,
    float* __restrict__ slots,
    const float* __restrict__ gmax,
    int nrows)
{
    __shared__ float2 s_mc[12];
    __shared__ float  s_blockmax[WAVES_PER_BLOCK];

    const int tid = threadIdx.x;
    if (tid < 12) s_mc[tid] = make_float2(coeffs_m[tid], coeffs_c[tid]);
    if (PASS == 0 && tid < WAVES_PER_BLOCK) s_blockmax[tid] = 0.0f;
    __syncthreads();

    const int wave = tid >> 6;
    const int lane = tid & 63;
    const int row  = blockIdx.x * WAVES_PER_BLOCK + wave;
    const bool active = (row < nrows);

    float S = 1.0f;
    float e[8];
    float4* op = nullptr;

    if (active) {
        // Interval lower edges 1..11 -> uniform loads -> SGPRs (edge 0 = -10 implied by clip).
        float aedge[11];
#pragma unroll
        for (int i = 0; i < 11; ++i) aedge[i] = intervals[i + 1];

        const float4* rp = reinterpret_cast<const float4*>(scores + (size_t)row * ROW_LEN);
        float4 v0 = rp[lane];
        float4 v1 = rp[lane + 64];
        float x[8] = {v0.x, v0.y, v0.z, v0.w, v1.x, v1.y, v1.z, v1.w};

        float mx = fmaxf(fmaxf(fmaxf(x[0], x[1]), fmaxf(x[2], x[3])),
                         fmaxf(fmaxf(x[4], x[5]), fmaxf(x[6], x[7])));
        mx = wave_reduce_max(mx);

        float sum = 0.0f;
#pragma unroll
        for (int j = 0; j < 8; ++j) {
            float sh = x[j] - mx;
            float t = rintf(sh * 67108864.0f);                  // Q32.26 snap
            t = fminf(fmaxf(t, -2147483648.0f), 2147483648.0f);
            float fx = t * 1.4901161193847656e-8f;              // * 2^-26 exact
            float xc = fminf(fmaxf(fx, -10.0f), 0.0f);
            int cnt = 0;
#pragma unroll
            for (int i = 0; i < 11; ++i) cnt += (xc >= aedge[i]) ? 1 : 0;
            int idx = min(cnt, 10);
            float2 p = s_mc[idx];
            float ev = p.x * xc + p.y;
            e[j] = ev;
            sum += ev;
        }
        sum = wave_reduce_sum(sum);
        S = sum + 1e-9f;
        op = reinterpret_cast<float4*>(out + (size_t)row * ROW_LEN);
    }

    if (PASS == 0) {
        // Row max element snaps to xc==0 exactly -> max|e| per row == coeffs_c[10].
        if (active && lane == 0) s_blockmax[wave] = coeffs_c[10] / S;
        __syncthreads();
        if (tid == 0) {
            float bm = s_blockmax[0];
#pragma unroll
            for (int w = 1; w < WAVES_PER_BLOCK; ++w) bm = fmaxf(bm, s_blockmax[w]);
            slots[blockIdx.x] = bm;      // plain store, overwritten every launch
        }
    } else if (active) {
        const float inv = 1.0f / S;
        const float am = *gmax;
        const float scale = fmaxf(am / 127.0f, 1e-8f);
        const float iscale = 1.0f / scale;
        float o[8];
#pragma unroll
        for (int j = 0; j < 8; ++j) {
            float sv = e[j] * inv;
            float q = fminf(fmaxf(rintf(sv * iscale), -127.0f), 127.0f) * scale;
            o[j] = q;
        }
        op[lane]      = make_float4(o[0], o[1], o[2], o[3]);
        op[lane + 64] = make_float4(o[4], o[5], o[6], o[7]);
    }
}

// Single-block reduce: slots[0..n) -> gmax[0]
__global__ __launch_bounds__(1024) void reduce_max_kernel(
    const float* __restrict__ slots, float* __restrict__ gmax, int n)
{
    __shared__ float s_w[16];
    const int tid = threadIdx.x;
    float m = 0.0f;
    for (int i = tid; i < n; i += 1024) m = fmaxf(m, slots[i]);
    m = wave_reduce_max(m);
    if ((tid & 63) == 0) s_w[tid >> 6] = m;
    __syncthreads();
    if (tid < 64) {
        float v = (tid < 16) ? s_w[tid] : 0.0f;
        v = wave_reduce_max(v);
        if (tid == 0) gmax[0] = v;
    }
}

extern "C" void kernel_launch(void* const* d_in, const int* in_sizes, int n_in,
                              void* d_out, int out_size, void* d_ws, size_t ws_size,
                              hipStream_t stream) {
    const float* scores    = (const float*)d_in[0];
    const float* coeffs_m  = (const float*)d_in[1];
    const float* coeffs_c  = (const float*)d_in[2];
    const float* intervals = (const float*)d_in[3];
    float* out = (float*)d_out;

    const int nrows  = in_sizes[0] / ROW_LEN;
    const int blocks = (nrows + WAVES_PER_BLOCK - 1) / WAVES_PER_BLOCK;

    float* slots = (float*)d_ws;          // [blocks] floats, fully written each launch
    float* gmax  = slots + blocks;        // [1] float, written by reduce kernel

    pla_softmax_kernel<0><<<blocks, THREADS, 0, stream>>>(
        scores, coeffs_m, coeffs_c, intervals, out, slots, gmax, nrows);
    reduce_max_kernel<<<1, 1024, 0, stream>>>(slots, gmax, blocks);
    pla_softmax_kernel<1><<<blocks, THREADS, 0, stream>>>(
        scores, coeffs_m, coeffs_c, intervals, out, slots, gmax, nrows);
}